// Round 15
// baseline (409.305 us; speedup 1.0000x reference)
//
#include <hip/hip_runtime.h>

typedef __attribute__((ext_vector_type(8))) short short8;
typedef __attribute__((ext_vector_type(4))) float f32x4;

#define MFMA16(a, b, c) __builtin_amdgcn_mfma_f32_16x16x32_bf16(a, b, c, 0, 0, 0)

__device__ __forceinline__ unsigned short f2bf(float x) {
  union { float f; unsigned u; } c; c.f = x;
  unsigned r = c.u + 0x7FFFu + ((c.u >> 16) & 1u);
  return (unsigned short)(r >> 16);
}
__device__ __forceinline__ float bf2f(unsigned short h) {
  union { unsigned u; float f; } c; c.u = ((unsigned)h) << 16; return c.f;
}
// Packed f32x2 -> 2xbf16 (RNE), gfx950 HW convert. low16 = first operand.
__device__ __forceinline__ unsigned cvtpk(float lo, float hi) {
  unsigned r;
  asm("v_cvt_pk_bf16_f32 %0, %1, %2" : "=v"(r) : "v"(lo), "v"(hi));
  return r;
}

// ---------------------------------------------------------------------------
// Workspace (bytes). Proven-safe peak (< 18,087,936).
// r25: d3w/c4w packed to 128 rows (2x64 split). ALL weights in k' order:
// k' = cb*144 + n*16 + ci_lo.
// LIVENESS (r12): pt5/pt6 live inside h1's span — k_packT after conv2.
// ---------------------------------------------------------------------------
static constexpr size_t PK_D1PW = 0;          // 32 x 1920
static constexpr size_t PK_D1W  = 122880;     // 96 x 1920
static constexpr size_t PK_C2W  = 491520;     // 96 x 896
static constexpr size_t PK_D3PW = 663552;     // 32 x 896
static constexpr size_t PK_D3W  = 720896;     // 128 x 896  (2x64 split rows)
static constexpr size_t PK_C4W  = 950272;     // 128 x 1024 (2x64 split rows; ends 1,212,416)
static constexpr size_t OFF1_B  = 2269184;    // bf16 [128,18,256]
static constexpr size_t H2P_B   = 2269184;    // f32 [128,96,64] (aliases off1)
static constexpr size_t H1_B    = 5414912;    // f32 [128,96,256] (ends 17,997,824)
static constexpr size_t OFF3_B  = 5414912;    // bf16 [128,18,64]
static constexpr size_t H3_B    = 5709824;    // f32 [128,108,64]
static constexpr size_t H4P_B   = 9248768;    // f32 [128,108,16]
static constexpr size_t H5_B    = 10133504;   // f32 [128,128,16]
static constexpr size_t H6P_B   = 11182080;   // f32 [128,512]
static constexpr size_t FCO_B   = 11444224;   // f32 [128,200] (ends 11,546,624)
static constexpr size_t PT5_B   = 11546624;   // f32 [972][128]   497,664
static constexpr size_t PT6_B   = 12044288;   // f32 [1152][128]  589,824 (ends 12,634,112)

// ---------------------------------------------------------------------------
// Weight pre-pack -> bf16 HI plane, ALL tensors in k' = cb*144 + n*16 + ci_lo.
// rows: d1pw 32, d1w 96, c2w 96, d3pw 32, d3w 128, c4w 128 (oc >= OC -> 0).
// ---------------------------------------------------------------------------
__global__ __launch_bounds__(256) void k_pack6(
    const float* __restrict__ s0, const float* __restrict__ s1,
    const float* __restrict__ s2, const float* __restrict__ s3,
    const float* __restrict__ s4, const float* __restrict__ s5,
    char* __restrict__ ws) {
  int blk = blockIdx.x;
  const float* src; unsigned short* dst; int K, Kp, OC, IC;
  if      (blk <  240) { src=s0; dst=(unsigned short*)(ws+PK_D1PW); OC=18;  K=1800; Kp=1920; IC=200; }
  else if (blk <  960) { src=s1; dst=(unsigned short*)(ws+PK_D1W);  OC=96;  K=1800; Kp=1920; IC=200; blk -= 240; }
  else if (blk < 1296) { src=s2; dst=(unsigned short*)(ws+PK_C2W);  OC=96;  K=864;  Kp=896;  IC=96;  blk -= 960; }
  else if (blk < 1408) { src=s3; dst=(unsigned short*)(ws+PK_D3PW); OC=18;  K=864;  Kp=896;  IC=96;  blk -= 1296; }
  else if (blk < 1856) { src=s4; dst=(unsigned short*)(ws+PK_D3W);  OC=108; K=864;  Kp=896;  IC=96;  blk -= 1408; }
  else                 { src=s5; dst=(unsigned short*)(ws+PK_C4W);  OC=108; K=972;  Kp=1024; IC=108; blk -= 1856; }
  int e = blk * 256 + threadIdx.x;
  int oc = e / Kp, k = e - oc * Kp;
  float v = 0.f;
  if (oc < OC) {
    int NCB = (IC + 15) >> 4;
    if (k < NCB * 144) {
      int cb = k / 144, r = k - cb*144;
      int n = r >> 4, ci = cb*16 + (r & 15);
      if (ci < IC) v = src[(size_t)oc*K + ci*9 + n];
    }
  }
  dst[e] = f2bf(v);
}

// Transpose c5w/c6w to [k][OC] f32 for the tail convs.
// NOTE: must run after conv2 (writes land inside h1's dead region).
__global__ __launch_bounds__(256) void k_packT(
    const float* __restrict__ s5, const float* __restrict__ s6,
    char* __restrict__ ws) {
  int e = blockIdx.x * 256 + threadIdx.x;
  if (e < 124416) {                       // c5: 972 x 128
    int k = e >> 7, oc = e & 127;
    ((float*)(ws + PT5_B))[e] = s5[(size_t)oc*972 + k];
  } else if (e < 124416 + 147456) {       // c6: 1152 x 128
    int e2 = e - 124416;
    int k = e2 >> 7, oc = e2 & 127;
    ((float*)(ws + PT6_B))[e2] = s6[(size_t)oc*1152 + k];
  }
}

// ---------------------------------------------------------------------------
// Deform MFMA GEMM — r21 schedule + MROWS/NSPL knobs.
// r26: X staged as BF16 [pos][16ci], row stride 24 shorts (48B). A corner's
// 8 channels = ONE b128 gather (was 2) -> gather LDS ops halve; stageX
// traffic halves. 48B stride: row bases r*12 mod 32 have period 8 with
// disjoint 4-bank spans -> consecutive-row b128s conflict-free (quad
// rotation dropped). Cost: +32 unpack VALU/slice (shl/and, cool pipe).
// Numerics: X quantized to bf16 BEFORE interpolation (~2^-9 rel, same
// magnitude as weight quantization).
// ---------------------------------------------------------------------------
template<int IC, int OC, int OCPAD, int NT, int H, int W, bool ROLLING,
         int MROWS = 64, int NSPL = 1>
__global__ __launch_bounds__(MROWS*4, 2) void k_dgemm(
    const float* __restrict__ in,              // [128,IC,H,W] f32
    const unsigned short* __restrict__ offb,   // [128,18,H,W] bf16
    const unsigned short* __restrict__ wpk,    // packed bf16-hi [NSPL*OCPAD][KPAD] k'
    const float* __restrict__ bng, const float* __restrict__ bnb,
    const float* __restrict__ bnm, const float* __restrict__ bnv,
    float* __restrict__ out) {                 // [128,OC,H,W] f32
  constexpr int NTH  = MROWS * 4;
  constexpr int HW   = H * W;
  constexpr int NCB  = (IC + 15) >> 4;
  constexpr int KV   = NCB * 144;
  constexpr int NP   = (KV + 63) / 64;
  constexpr int KPAD = NP * 64;
  constexpr int TILES = HW / MROWS;
  constexpr int HP = H + 2, WPD = W + 2;
  constexpr int BSZ = OCPAD * 64 * 2;          // [8 kgrp][OCPAD][8] bf16
  constexpr int SRX = 24;                      // shorts per pos (48B row)
  constexpr int CHUNKS = HW * SRX;             // shorts per 16-ch chunk
  constexpr int SLOTS  = ROLLING ? 2 : NCB;
  constexpr int XSZ    = SLOTS * CHUNKS * 2;   // bytes
  constexpr int TBL  = MROWS * 9;
  constexpr int TIDX = TBL * 4, TWT = TBL * 16;
  constexpr int PBYTES = TIDX + TWT + BSZ + XSZ;
  constexpr int NBV = (OCPAD * 8 + NTH - 1) / NTH;
  __shared__ __align__(16) char pool[PBYTES];
  uchar4* s_idx = (uchar4*)pool;
  float4* s_wt  = (float4*)(pool + TIDX);
  unsigned short* s_bh = (unsigned short*)(pool + TIDX + TWT);
  unsigned short* s_xt = (unsigned short*)(pool + TIDX + TWT + BSZ);

  const int tid = threadIdx.x;
  const int grp = blockIdx.x % (TILES * NSPL);
  const int b   = blockIdx.x / (TILES * NSPL);
  const int hw0 = (grp / NSPL) * MROWS;
  const int ns  = grp % NSPL;
  const int oc0 = ns * OCPAD;                  // this block's oc base
  const unsigned short* __restrict__ wpk_s = wpk + (size_t)oc0 * KPAD;
  const float* __restrict__ inb = in + (size_t)b * IC * HW;

  // bilinear table (exact reference formulas; zero-pad folded into weights)
  for (int i = tid; i < TBL; i += NTH) {
    int px2 = i / 9, n = i % 9;
    int h = (hw0 + px2) / W, w = (hw0 + px2) % W;
    float offx = bf2f(offb[(((size_t)b*18 + n)*HW) + h*W + w]);
    float offy = bf2f(offb[(((size_t)b*18 + 9 + n)*HW) + h*W + w]);
    float pxv = (float)(h + n/3) + offx;
    float pyv = (float)(w + n%3) + offy;
    pxv = fminf(fmaxf(pxv, 0.f), (float)(HP - 1));
    pyv = fminf(fmaxf(pyv, 0.f), (float)(WPD - 1));
    float x0 = floorf(pxv), y0 = floorf(pyv);
    float x1 = fminf(x0 + 1.f, (float)(HP - 1));
    float y1 = fminf(y0 + 1.f, (float)(WPD - 1));
    float glt = (1.f + x0 - pxv) * (1.f + y0 - pyv);
    float grb = (1.f - x1 + pxv) * (1.f - y1 + pyv);
    float glb = (1.f + x0 - pxv) * (1.f - y1 + pyv);
    float grt = (1.f - x1 + pxv) * (1.f + y0 - pyv);
    int   cx[4] = {(int)x0, (int)x1, (int)x0, (int)x1};
    int   cy[4] = {(int)y0, (int)y1, (int)y1, (int)y0};
    float gw[4] = {glt, grb, glb, grt};
    unsigned char id[4]; float gg[4];
#pragma unroll
    for (int q = 0; q < 4; ++q) {
      bool ok = (cx[q] >= 1) && (cx[q] <= H) && (cy[q] >= 1) && (cy[q] <= W);
      id[q] = ok ? (unsigned char)((cx[q]-1)*W + (cy[q]-1)) : (unsigned char)0;
      gg[q] = ok ? gw[q] : 0.f;
    }
    s_idx[i] = make_uchar4(id[0], id[1], id[2], id[3]);
    s_wt[i]  = make_float4(gg[0], gg[1], gg[2], gg[3]);
  }

  // stage one 16-channel chunk as bf16 [pos][16ci] (stride SRX shorts).
  auto stageX = [&](int cb) {
    const int slot = ROLLING ? (cb & 1) : cb;
    unsigned short* dst = s_xt + (size_t)slot * CHUNKS;
    for (int u = tid; u < HW * 2; u += NTH) {
      const int pp = u & (HW - 1);
      const int h  = u / HW;                   // which 8-ci half
      unsigned q[4];
#pragma unroll
      for (int i2 = 0; i2 < 4; ++i2) {
        int ci = cb*16 + h*8 + i2*2;
        float f0 = (ci     < IC) ? inb[(size_t)ci*HW + pp]     : 0.f;
        float f1 = (ci + 1 < IC) ? inb[(size_t)(ci+1)*HW + pp] : 0.f;
        q[i2] = cvtpk(f0, f1);
      }
      *(uint4*)(dst + (size_t)pp*SRX + h*8) = make_uint4(q[0], q[1], q[2], q[3]);
    }
  };
  if (ROLLING) stageX(0);
  else { for (int cb = 0; cb < NCB; ++cb) stageX(cb); }
  int staged = 0;

  const int lane = tid & 63;
  const int wv   = tid >> 6;
  const int m16  = lane & 15;
  const int quad = lane >> 4;
  const int pv   = wv*16 + m16;          // this thread's MFMA A row (pixel)
  const int tbase = pv * 9;
  f32x4 acc[NT];
#pragma unroll
  for (int nt = 0; nt < NT; ++nt) acc[nt] = (f32x4){0.f, 0.f, 0.f, 0.f};
  short8 rb[NBV];

  auto prefB = [&](int p) {
    if (p >= NP) return;
    const int k0 = p * 64;
#pragma unroll
    for (int j = 0; j < NBV; ++j) {
      int e = tid + NTH*j;
      if (e < OCPAD*8) {
        int oc = e >> 3, kq = e & 7;
        rb[j] = *(const short8*)(wpk_s + (size_t)oc*KPAD + k0 + kq*8);
      }
    }
  };
  auto commitB = [&]() {
#pragma unroll
    for (int j = 0; j < NBV; ++j) {
      int e = tid + NTH*j;
      if (e < OCPAD*8) {
        int oc = e >> 3, kq = e & 7;
        *(short8*)&s_bh[(kq*OCPAD + (oc ^ ((kq*2)&7)))*8] = rb[j];
      }
    }
  };

  // Build one 8-wide A slice (k' = kk..kk+7) for pixel pv, in registers.
  // bf16 staging: each corner's 8 channels = ONE b128; unpack + weighted sum.
  auto buildA = [&](int kk, short8& ahv, short8& alv) {
    float v[8];
#pragma unroll
    for (int i = 0; i < 8; ++i) v[i] = 0.f;
    if (kk < KV) {
      const int cb2 = kk / 144;
      const int rem = kk - cb2*144;
      const int n   = rem >> 4;
      const int gh  = (rem >> 3) & 1;          // which 8-ci half
      const int slot = ROLLING ? (cb2 & 1) : cb2;
      const unsigned short* xb = s_xt + (size_t)slot * CHUNKS;
      uchar4 t4 = s_idx[tbase + n];
      float4 w4 = s_wt[tbase + n];
      uint4 c0 = *(const uint4*)(xb + (size_t)t4.x*SRX + gh*8);
      uint4 c1 = *(const uint4*)(xb + (size_t)t4.y*SRX + gh*8);
      uint4 c2 = *(const uint4*)(xb + (size_t)t4.z*SRX + gh*8);
      uint4 c3 = *(const uint4*)(xb + (size_t)t4.w*SRX + gh*8);
      auto addc = [&](uint4 c, float wq) {
        v[0] += wq*__uint_as_float(c.x << 16); v[1] += wq*__uint_as_float(c.x & 0xFFFF0000u);
        v[2] += wq*__uint_as_float(c.y << 16); v[3] += wq*__uint_as_float(c.y & 0xFFFF0000u);
        v[4] += wq*__uint_as_float(c.z << 16); v[5] += wq*__uint_as_float(c.z & 0xFFFF0000u);
        v[6] += wq*__uint_as_float(c.w << 16); v[7] += wq*__uint_as_float(c.w & 0xFFFF0000u);
      };
      addc(c0, w4.x); addc(c1, w4.y); addc(c2, w4.z); addc(c3, w4.w);
    }
    unsigned hp[4], lp[4];
#pragma unroll
    for (int i = 0; i < 4; ++i) {
      unsigned h = cvtpk(v[2*i], v[2*i+1]);
      float h0 = __uint_as_float(h << 16);
      float h1 = __uint_as_float(h & 0xFFFF0000u);
      hp[i] = h;
      lp[i] = cvtpk(v[2*i] - h0, v[2*i+1] - h1);
    }
    uint4 uh = make_uint4(hp[0], hp[1], hp[2], hp[3]);
    uint4 ul = make_uint4(lp[0], lp[1], lp[2], lp[3]);
    ahv = *(short8*)&uh;
    alv = *(short8*)&ul;
  };

  prefB(0);
  __syncthreads();

  for (int p = 0; p < NP; ++p) {
    short8 ah[2], al[2];
    buildA(p*64 +      quad*8, ah[0], al[0]);
    buildA(p*64 + 32 + quad*8, ah[1], al[1]);
    commitB();
    if (ROLLING) {
      // folded roll staging: no extra barriers (safety proof r21)
      int want = ((p + 1) * 64 + 63) / 144;
      if (want >= NCB) want = NCB - 1;
      if (want > staged) { stageX(want); staged = want; }
    }
    prefB(p + 1);
    __syncthreads();   // writes (commitB/stageX) visible; phase boundary
#pragma unroll
    for (int ks = 0; ks < 2; ++ks) {
      const int kg = ks*4 + quad;
      const int xm = (kg*2) & 7;
#pragma unroll
      for (int nt = 0; nt < NT; ++nt) {
        short8 bh = *(const short8*)&s_bh[(kg*OCPAD + ((nt*16 + m16) ^ xm))*8];
        acc[nt] = MFMA16(ah[ks], bh, acc[nt]);
        acc[nt] = MFMA16(al[ks], bh, acc[nt]);
      }
    }
    __syncthreads();   // read phase done before next iter's writes
  }

  // epilogue: BN + ReLU, f32 out
#pragma unroll
  for (int nt = 0; nt < NT; ++nt) {
    int oc = oc0 + nt*16 + m16;
    if (oc < OC) {
      float sc = bng[oc] * rsqrtf(bnv[oc] + 1e-5f);
      float sh = bnb[oc] - bnm[oc] * sc;
#pragma unroll
      for (int reg = 0; reg < 4; ++reg) {
        int rowl = wv*16 + quad*4 + reg;
        float e = fmaxf(acc[nt][reg] * sc + sh, 0.f);
        out[((size_t)b*OC + oc)*HW + hw0 + rowl] = e;
      }
    }
  }
}

// ---------------------------------------------------------------------------
// Conv MFMA GEMM — r21 form + r25 NSPL (oc-split across blocks; split's
// duplicate staging/buildV lands on otherwise-idle CUs for the 128-block
// layers). s_out/pooling localized to this block's oc range.
// ---------------------------------------------------------------------------
template<int IC, int OC, int OCPAD, int NT, int H, int W,
         bool HASBIAS, bool HASBN, bool RELU, int OUTMODE, int MINW, bool ALO,
         int NSPL = 1>
__global__ __launch_bounds__(256, MINW) void k_gemm(
    const float* __restrict__ in,
    const unsigned short* __restrict__ wpk,    // packed bf16-hi [NSPL*OCPAD][KPAD] k'
    const float* __restrict__ bias,
    const float* __restrict__ bng, const float* __restrict__ bnb,
    const float* __restrict__ bnm, const float* __restrict__ bnv,
    void* __restrict__ outv) {
  constexpr int HW   = H * W;
  constexpr int NCB  = (IC + 15) >> 4;
  constexpr int KV   = NCB * 144;
  constexpr int NP   = (KV + 63) / 64;
  constexpr int KPAD = NP * 64;
  constexpr int TILES = HW / 64;
  constexpr int RT   = 64 / W;               // tile rows
  constexpr int HR   = RT + 2, WPD = W + 2;  // halo dims
  constexpr int HPOS = HR * WPD;
  constexpr int SROW = 20;                   // floats per halo position
  constexpr int CHUNKF = HPOS * SROW;
  constexpr int XSZ  = 2 * CHUNKF * 4;       // 2 rolling slots
  constexpr int BSLOT = OCPAD * 64;          // shorts per B slot
  constexpr int BSZ  = 2 * BSLOT * 2;        // 2 slots
  constexpr int PBST = BSZ + XSZ;
  constexpr int SOUTB = (OUTMODE == 2) ? 64 * (OCPAD + 1) * 4 : 0;
  constexpr int PBYTES = (PBST > SOUTB) ? PBST : SOUTB;
  constexpr int NBV = (OCPAD * 8 + 255) / 256;
  __shared__ __align__(16) char pool[PBYTES];
  unsigned short* s_bh = (unsigned short*)pool;
  float* s_xt  = (float*)(pool + BSZ);
  float* s_out = (float*)pool;

  const int tid = threadIdx.x;
  const int grp = blockIdx.x % (TILES * NSPL);
  const int b   = blockIdx.x / (TILES * NSPL);
  const int hw0 = (grp / NSPL) * 64;
  const int ns  = grp % NSPL;
  const int oc0 = ns * OCPAD;                // this block's oc base
  const unsigned short* __restrict__ wpk_s = wpk + (size_t)oc0 * KPAD;
  const int r0  = hw0 / W;                   // first image row of tile
  const float* __restrict__ inb = in + (size_t)b * IC * HW;

  const int lane = tid & 63;
  const int wv   = tid >> 6;
  const int m16  = lane & 15;
  const int quad = lane >> 4;
  const int pv   = wv*16 + m16;              // MFMA A row (tile-local pixel)
  const int lr   = pv / W, lc = pv % W;
  f32x4 acc[NT];
#pragma unroll
  for (int nt = 0; nt < NT; ++nt) acc[nt] = (f32x4){0.f, 0.f, 0.f, 0.f};
  short8 rb[NBV];

  // stage chunk cb as zero-padded halo [hpos][16ci] (stride SROW).
  auto stageX = [&](int cb) {
    float* dst = s_xt + (size_t)(cb & 1) * CHUNKF;
    for (int e = tid; e < HPOS * 4; e += 256) {
      int pos = e >> 2, g = e & 3;
      int hr = pos / WPD, hc = pos % WPD;
      int ir = r0 + hr - 1, ic = hc - 1;
      bool okp = (ir >= 0) && (ir < H) && (ic >= 0) && (ic < W);
      float4 v4;
#pragma unroll
      for (int i2 = 0; i2 < 4; ++i2) {
        int ci = cb*16 + g*4 + i2;
        ((float*)&v4)[i2] = (okp && ci < IC) ? inb[(size_t)ci*HW + ir*W + ic] : 0.f;
      }
      *(float4*)(dst + (size_t)pos*SROW + g*4) = v4;
    }
  };

  auto prefB = [&](int p) {
    if (p >= NP) return;
    const int k0 = p * 64;
#pragma unroll
    for (int j = 0; j < NBV; ++j) {
      int e = tid + 256*j;
      if (e < OCPAD*8) {
        int oc = e >> 3, kq = e & 7;
        rb[j] = *(const short8*)(wpk_s + (size_t)oc*KPAD + k0 + kq*8);
      }
    }
  };
  auto commitB = [&](int slot) {
    unsigned short* sb = s_bh + (size_t)slot * BSLOT;
#pragma unroll
    for (int j = 0; j < NBV; ++j) {
      int e = tid + 256*j;
      if (e < OCPAD*8) {
        int oc = e >> 3, kq = e & 7;
        *(short8*)&sb[(kq*OCPAD + (oc ^ ((kq*2)&7)))*8] = rb[j];
      }
    }
  };

  // Build one 8-wide A slice (k' = kk..kk+7): 8 consecutive ci at tap n.
  auto buildV = [&](int kk, short8& ahv, short8& alv) {
    float v[8];
    if (kk < KV) {
      const int cb2 = kk / 144;
      const int rem = kk - cb2*144;
      const int n   = rem >> 4;
      const int g0  = (rem >> 2) & 2;        // 0 or 2: which 8-ci half
      const float* xb = s_xt + (size_t)(cb2 & 1) * CHUNKF;
      const int hpos = (lr + n/3) * WPD + (lc + n%3);
      const float* rowp = xb + (size_t)hpos * SROW;
      float4 a0 = *(const float4*)(rowp + g0*4);
      float4 a1 = *(const float4*)(rowp + (g0+1)*4);
      v[0]=a0.x; v[1]=a0.y; v[2]=a0.z; v[3]=a0.w;
      v[4]=a1.x; v[5]=a1.y; v[6]=a1.z; v[7]=a1.w;
    } else {
#pragma unroll
      for (int i = 0; i < 8; ++i) v[i] = 0.f;
    }
    unsigned hp[4], lp[4];
#pragma unroll
    for (int i = 0; i < 4; ++i) {
      unsigned h = cvtpk(v[2*i], v[2*i+1]);
      hp[i] = h;
      if constexpr (ALO) {
        float h0 = __uint_as_float(h << 16);
        float h1 = __uint_as_float(h & 0xFFFF0000u);
        lp[i] = cvtpk(v[2*i] - h0, v[2*i+1] - h1);
      }
    }
    uint4 uh = make_uint4(hp[0], hp[1], hp[2], hp[3]);
    ahv = *(short8*)&uh;
    if constexpr (ALO) {
      uint4 ul = make_uint4(lp[0], lp[1], lp[2], lp[3]);
      alv = *(short8*)&ul;
    }
  };

  stageX(0);
  prefB(0);
  int staged = 0;
  __syncthreads();

  for (int p = 0; p < NP; ++p) {
    short8 ah[2], al[2];
    buildV(p*64 +      quad*8, ah[0], al[0]);
    buildV(p*64 + 32 + quad*8, ah[1], al[1]);
    commitB(p & 1);
    prefB(p + 1);
    {   // roll staging (block-uniform condition; opposite x-slot)
      int want = ((p + 1) * 64 + 63) / 144;
      if (want >= NCB) want = NCB - 1;
      if (want > staged) { stageX(want); staged = want; }
    }
    __syncthreads();   // B[p] + staged chunk visible; prev-iter reads done
    const unsigned short* sb = s_bh + (size_t)(p & 1) * BSLOT;
#pragma unroll
    for (int ks = 0; ks < 2; ++ks) {
      const int kg = ks*4 + quad;
      const int xm = (kg*2) & 7;
#pragma unroll
      for (int nt = 0; nt < NT; ++nt) {
        short8 bh = *(const short8*)&sb[(kg*OCPAD + ((nt*16 + m16) ^ xm))*8];
        acc[nt] = MFMA16(ah[ks], bh, acc[nt]);
        if constexpr (ALO) acc[nt] = MFMA16(al[ks], bh, acc[nt]);
      }
    }
  }

  constexpr int OCS = OCPAD + 1;
  if constexpr (OUTMODE == 2) {
    __syncthreads();   // lagging MFMA reads of s_bh done before s_out clobbers
  }
#pragma unroll
  for (int nt = 0; nt < NT; ++nt) {
    int ocl = nt*16 + m16;
    int oc  = oc0 + ocl;
    float bi = 0.f, sc = 1.f, sh = 0.f;
    if (oc < OC) {
      if constexpr (HASBIAS) bi = bias[oc];
      if constexpr (HASBN) {
        sc = bng[oc] * rsqrtf(bnv[oc] + 1e-5f);
        sh = bnb[oc] - bnm[oc] * sc;
      }
    }
#pragma unroll
    for (int reg = 0; reg < 4; ++reg) {
      int rowl = wv*16 + quad*4 + reg;
      float e = (acc[nt][reg] + bi) * sc + sh;
      if constexpr (RELU) e = fmaxf(e, 0.f);
      if (oc < OC) {
        if constexpr (OUTMODE == 1) {
          ((unsigned short*)outv)[((size_t)b*OC + oc)*HW + hw0 + rowl] = f2bf(e);
        } else {
          s_out[rowl*OCS + ocl] = e;
        }
      }
    }
  }
  if constexpr (OUTMODE == 2) {
    __syncthreads();
    constexpr int PR = (64 / W) / 2, PC = W / 2;
    const int OCL = (OC - oc0 < OCPAD) ? (OC - oc0) : OCPAD;
    const int CNT = PR * PC * OCL;
    float* out = (float*)outv;
    for (int e2 = tid; e2 < CNT; e2 += 256) {
      int ocl = e2 % OCL, q = e2 / OCL, pc2 = q % PC, pr2 = q / PC;
      int base = ((2*pr2)*W + 2*pc2)*OCS + ocl;
      float a0 = s_out[base],         a1 = s_out[base + OCS];
      float a2 = s_out[base + W*OCS], a3 = s_out[base + W*OCS + OCS];
      float m = fmaxf(fmaxf(a0, a1), fmaxf(a2, a3));
      out[(((size_t)b*OC + oc0 + ocl)*(H/2) + (r0 >> 1) + pr2)*(W/2) + pc2] = m;
    }
  }
}

// ---------------------------------------------------------------------------
// Tail conv (4x4 spatial): block = (batch, 32-oc group), ONE barrier.
// Input staged zero-padded 6x6 per channel; weights pre-transposed [k][OC].
// Thread = (oc, 2-pixel row pair). POOLAVG fuses ReLU-then-avgpool via
// __shfl_xor(.,2) (partner pixel-pair is 2 lanes away) -> writes [b][512].
// ---------------------------------------------------------------------------
template<int IC, int OC, bool POOLAVG>
__global__ __launch_bounds__(256, 4) void k_tail(
    const float* __restrict__ in,     // [128, IC, 4, 4]
    const float* __restrict__ wt,     // [IC*9][OC] f32 (transposed)
    const float* __restrict__ bias,
    const float* __restrict__ bng, const float* __restrict__ bnb,
    const float* __restrict__ bnm, const float* __restrict__ bnv,
    float* __restrict__ out) {
  constexpr int NB = OC / 32;
  __shared__ float s_pad[IC * 36];
  const int tid = threadIdx.x;
  const int b = blockIdx.x / NB;
  const int g = blockIdx.x % NB;
  for (int i = tid; i < IC*36; i += 256) {
    int ci = i / 36, pos = i % 36;
    int rr = pos / 6 - 1, cc = pos % 6 - 1;
    bool ok = (rr >= 0) && (rr < 4) && (cc >= 0) && (cc < 4);
    s_pad[i] = ok ? in[((size_t)b*IC + ci)*16 + rr*4 + cc] : 0.f;
  }
  __syncthreads();
  const int oc = g*32 + (tid >> 3);
  const int p  = tid & 7;                 // pixel-pair index
  const int r0 = p >> 1, c0 = (p & 1) * 2;
  float a0 = 0.f, a1 = 0.f;
  const float* wp = wt + oc;
#pragma unroll 2
  for (int ci = 0; ci < IC; ++ci) {
    const float* sp = s_pad + ci*36 + r0*6 + c0;
#pragma unroll
    for (int n = 0; n < 9; ++n) {
      float wv = wp[(size_t)(ci*9 + n)*OC];
      float v0 = sp[(n/3)*6 + (n%3)];
      float v1 = sp[(n/3)*6 + (n%3) + 1];
      a0 = fmaf(wv, v0, a0);
      a1 = fmaf(wv, v1, a1);
    }
  }
  float sc = bng[oc] * rsqrtf(bnv[oc] + 1e-5f);
  float sh = bnb[oc] - bnm[oc]*sc;
  float bi = bias[oc];
  float e0 = fmaxf((a0 + bi)*sc + sh, 0.f);
  float e1 = fmaxf((a1 + bi)*sc + sh, 0.f);
  if constexpr (!POOLAVG) {
    size_t ob = ((size_t)b*OC + oc)*16 + r0*4 + c0;
    out[ob]     = e0;
    out[ob + 1] = e1;
  } else {
    float s = e0 + e1;
    float tot = s + __shfl_xor(s, 2);
    if ((p & 2) == 0) {
      int pr = p >> 2, pc = p & 1;
      out[(size_t)b*512 + oc*4 + pr*2 + pc] = tot * 0.25f;
    }
  }
}

__global__ __launch_bounds__(128) void k_fc(const float* __restrict__ in,
                                            const float* __restrict__ w,
                                            const float* __restrict__ bias,
                                            float* __restrict__ out) {
  int j = blockIdx.x, b = threadIdx.x;
  const float4* ib = (const float4*)(in + (size_t)b*512);
  const float4* wb = (const float4*)(w + (size_t)j*512);
  float acc = bias[j];
  for (int k = 0; k < 128; ++k) {
    float4 a = ib[k], q = wb[k];
    acc = fmaf(a.x, q.x, fmaf(a.y, q.y, fmaf(a.z, q.z, fmaf(a.w, q.w, acc))));
  }
  out[(size_t)b*200 + j] = acc;
}

__global__ __launch_bounds__(128) void k_fc1(const float* __restrict__ in,
                                             const float* __restrict__ w,
                                             const float* __restrict__ bias,
                                             float* __restrict__ out) {
  int j = blockIdx.x, b = threadIdx.x;
  const float4* ib = (const float4*)(in + (size_t)b*200);
  const float4* wb = (const float4*)(w + (size_t)j*200);
  float acc = bias[j];
  for (int k = 0; k < 50; ++k) {
    float4 a = ib[k], q = wb[k];
    acc = fmaf(a.x, q.x, fmaf(a.y, q.y, fmaf(a.z, q.z, fmaf(a.w, q.w, acc))));
  }
  out[(size_t)b*16 + j] = acc;
}

// ---------------------------------------------------------------------------
extern "C" void kernel_launch(void* const* d_in, const int* in_sizes, int n_in,
                              void* d_out, int out_size, void* d_ws, size_t ws_size,
                              hipStream_t stream) {
  const float* X    = (const float*)d_in[0];
  const float* D1PW = (const float*)d_in[1];
  const float* D1PB = (const float*)d_in[2];
  const float* D1W  = (const float*)d_in[3];
  const float* BN1G = (const float*)d_in[4];
  const float* BN1B = (const float*)d_in[5];
  const float* BN1M = (const float*)d_in[6];
  const float* BN1V = (const float*)d_in[7];
  const float* C2W  = (const float*)d_in[8];
  const float* C2B  = (const float*)d_in[9];
  const float* BN2G = (const float*)d_in[10];
  const float* BN2B = (const float*)d_in[11];
  const float* BN2M = (const float*)d_in[12];
  const float* BN2V = (const float*)d_in[13];
  const float* D3PW = (const float*)d_in[14];
  const float* D3PB = (const float*)d_in[15];
  const float* D3W  = (const float*)d_in[16];
  const float* BN3G = (const float*)d_in[17];
  const float* BN3B = (const float*)d_in[18];
  const float* BN3M = (const float*)d_in[19];
  const float* BN3V = (const float*)d_in[20];
  const float* C4W  = (const float*)d_in[21];
  const float* C4B  = (const float*)d_in[22];
  const float* BN4G = (const float*)d_in[23];
  const float* BN4B = (const float*)d_in[24];
  const float* BN4M = (const float*)d_in[25];
  const float* BN4V = (const float*)d_in[26];
  const float* C5W  = (const float*)d_in[27];
  const float* C5B  = (const float*)d_in[28];
  const float* BN5G = (const float*)d_in[29];
  const float* BN5B = (const float*)d_in[30];
  const float* BN5M = (const float*)d_in[31];
  const float* BN5V = (const float*)d_in[32];
  const float* C6W  = (const float*)d_in[33];
  const float* C6B  = (const float*)d_in[34];
  const float* BN6G = (const float*)d_in[35];
  const float* BN6B = (const float*)d_in[36];
  const float* BN6M = (const float*)d_in[37];
  const float* BN6V = (const float*)d_in[38];
  const float* FCW  = (const float*)d_in[39];
  const float* FCB  = (const float*)d_in[40];
  const float* FC1W = (const float*)d_in[41];
  const float* FC1B = (const float*)d_in[42];

  char* ws = (char*)d_ws;
  unsigned short* pk_d1pw = (unsigned short*)(ws + PK_D1PW);
  unsigned short* pk_d1w  = (unsigned short*)(ws + PK_D1W);
  unsigned short* pk_c2w  = (unsigned short*)(ws + PK_C2W);
  unsigned short* pk_d3pw = (unsigned short*)(ws + PK_D3PW);
  unsigned short* pk_d3w  = (unsigned short*)(ws + PK_D3W);
  unsigned short* pk_c4w  = (unsigned short*)(ws + PK_C4W);
  unsigned short* off1 = (unsigned short*)(ws + OFF1_B);
  unsigned short* off3 = (unsigned short*)(ws + OFF3_B);
  float* h1   = (float*)(ws + H1_B);
  float* h2p  = (float*)(ws + H2P_B);
  float* h3   = (float*)(ws + H3_B);
  float* h4p  = (float*)(ws + H4P_B);
  float* h5   = (float*)(ws + H5_B);
  float* h6p  = (float*)(ws + H6P_B);
  float* fco  = (float*)(ws + FCO_B);
  float* pt5  = (float*)(ws + PT5_B);
  float* pt6  = (float*)(ws + PT6_B);
  float* outp = (float*)d_out;

  // weight pre-pack (bf16 hi planes; ALL tensors k' order; d3w/c4w 128 rows)
  k_pack6<<<2368, 256, 0, stream>>>(D1PW, D1W, C2W, D3PW, D3W, C4W, ws);

  // block 1: offset conv (A-hi only) -> deform einsum + BN + ReLU
  k_gemm<200,18,32,2,16,16,true,false,false,1,3,false><<<512, 256, 0, stream>>>(
      X, pk_d1pw, D1PB, nullptr, nullptr, nullptr, nullptr, off1);
  // dgemm1: MROWS=128 + r26 bf16-X staging
  k_dgemm<200,96,96,6,16,16,true,128><<<256, 512, 0, stream>>>(
      X, off1, pk_d1w, BN1G, BN1B, BN1M, BN1V, h1);
  // block 2: conv + bias + BN + ReLU + maxpool
  k_gemm<96,96,96,6,16,16,true,true,true,2,3,true><<<512, 256, 0, stream>>>(
      h1, pk_c2w, C2B, BN2G, BN2B, BN2M, BN2V, h2p);
  // tail-conv weight transpose — h1 now dead; pt5/pt6 live inside its span
  k_packT<<<1062, 256, 0, stream>>>(C5W, C6W, ws);
  // block 3: offset conv, NSPL=2 (grid 128->256)
  k_gemm<96,18,16,1,8,8,true,false,false,1,3,false,2><<<256, 256, 0, stream>>>(
      h2p, pk_d3pw, D3PB, nullptr, nullptr, nullptr, nullptr, off3);
  // dgemm3: NSPL=2 + r26 bf16-X staging
  k_dgemm<96,108,64,4,8,8,false,64,2><<<256, 256, 0, stream>>>(
      h2p, off3, pk_d3w, BN3G, BN3B, BN3M, BN3V, h3);
  // block 4: conv + maxpool, NSPL=2 (grid 128->256)
  k_gemm<108,108,64,4,8,8,true,true,true,2,3,true,2><<<256, 256, 0, stream>>>(
      h3, pk_c4w, C4B, BN4G, BN4B, BN4M, BN4V, h4p);
  // block 5: conv + BN + ReLU (tail, 512 blocks)
  k_tail<108,128,false><<<512, 256, 0, stream>>>(
      h4p, pt5, C5B, BN5G, BN5B, BN5M, BN5V, h5);
  // block 6: conv + BN + ReLU + avgpool (tail, fused)
  k_tail<128,128,true><<<512, 256, 0, stream>>>(
      h5, pt6, C6B, BN6G, BN6B, BN6M, BN6V, h6p);
  // classifier
  k_fc<<<200, 128, 0, stream>>>(h6p, FCW, FCB, fco);
  k_fc1<<<16, 128, 0, stream>>>(fco, FC1W, FC1B, outp);
}

// Round 16
// 401.993 us; speedup vs baseline: 1.0182x; 1.0182x over previous
//
#include <hip/hip_runtime.h>

typedef __attribute__((ext_vector_type(8))) short short8;
typedef __attribute__((ext_vector_type(4))) float f32x4;

#define MFMA16(a, b, c) __builtin_amdgcn_mfma_f32_16x16x32_bf16(a, b, c, 0, 0, 0)

__device__ __forceinline__ unsigned short f2bf(float x) {
  union { float f; unsigned u; } c; c.f = x;
  unsigned r = c.u + 0x7FFFu + ((c.u >> 16) & 1u);
  return (unsigned short)(r >> 16);
}
__device__ __forceinline__ float bf2f(unsigned short h) {
  union { unsigned u; float f; } c; c.u = ((unsigned)h) << 16; return c.f;
}
// Packed f32x2 -> 2xbf16 (RNE), gfx950 HW convert. low16 = first operand.
__device__ __forceinline__ unsigned cvtpk(float lo, float hi) {
  unsigned r;
  asm("v_cvt_pk_bf16_f32 %0, %1, %2" : "=v"(r) : "v"(lo), "v"(hi));
  return r;
}

// ---------------------------------------------------------------------------
// Workspace (bytes). Proven-safe peak (< 18,087,936).
// r25: d3w/c4w packed to 128 rows (2x64 split). ALL weights in k' order:
// k' = cb*144 + n*16 + ci_lo.
// LIVENESS (r12): pt5/pt6 live inside h1's span — k_packT after conv2.
// ---------------------------------------------------------------------------
static constexpr size_t PK_D1PW = 0;          // 32 x 1920
static constexpr size_t PK_D1W  = 122880;     // 96 x 1920
static constexpr size_t PK_C2W  = 491520;     // 96 x 896
static constexpr size_t PK_D3PW = 663552;     // 32 x 896
static constexpr size_t PK_D3W  = 720896;     // 128 x 896  (2x64 split rows)
static constexpr size_t PK_C4W  = 950272;     // 128 x 1024 (2x64 split rows; ends 1,212,416)
static constexpr size_t OFF1_B  = 2269184;    // bf16 [128,18,256]
static constexpr size_t H2P_B   = 2269184;    // f32 [128,96,64] (aliases off1)
static constexpr size_t H1_B    = 5414912;    // f32 [128,96,256] (ends 17,997,824)
static constexpr size_t OFF3_B  = 5414912;    // bf16 [128,18,64]
static constexpr size_t H3_B    = 5709824;    // f32 [128,108,64]
static constexpr size_t H4P_B   = 9248768;    // f32 [128,108,16]
static constexpr size_t H5_B    = 10133504;   // f32 [128,128,16]
static constexpr size_t H6P_B   = 11182080;   // f32 [128,512]
static constexpr size_t FCO_B   = 11444224;   // f32 [128,200] (ends 11,546,624)
static constexpr size_t PT5_B   = 11546624;   // f32 [972][128]   497,664
static constexpr size_t PT6_B   = 12044288;   // f32 [1152][128]  589,824 (ends 12,634,112)

// ---------------------------------------------------------------------------
// Weight pre-pack -> bf16 HI plane, ALL tensors in k' = cb*144 + n*16 + ci_lo.
// rows: d1pw 32, d1w 96, c2w 96, d3pw 32, d3w 128, c4w 128 (oc >= OC -> 0).
// ---------------------------------------------------------------------------
__global__ __launch_bounds__(256) void k_pack6(
    const float* __restrict__ s0, const float* __restrict__ s1,
    const float* __restrict__ s2, const float* __restrict__ s3,
    const float* __restrict__ s4, const float* __restrict__ s5,
    char* __restrict__ ws) {
  int blk = blockIdx.x;
  const float* src; unsigned short* dst; int K, Kp, OC, IC;
  if      (blk <  240) { src=s0; dst=(unsigned short*)(ws+PK_D1PW); OC=18;  K=1800; Kp=1920; IC=200; }
  else if (blk <  960) { src=s1; dst=(unsigned short*)(ws+PK_D1W);  OC=96;  K=1800; Kp=1920; IC=200; blk -= 240; }
  else if (blk < 1296) { src=s2; dst=(unsigned short*)(ws+PK_C2W);  OC=96;  K=864;  Kp=896;  IC=96;  blk -= 960; }
  else if (blk < 1408) { src=s3; dst=(unsigned short*)(ws+PK_D3PW); OC=18;  K=864;  Kp=896;  IC=96;  blk -= 1296; }
  else if (blk < 1856) { src=s4; dst=(unsigned short*)(ws+PK_D3W);  OC=108; K=864;  Kp=896;  IC=96;  blk -= 1408; }
  else                 { src=s5; dst=(unsigned short*)(ws+PK_C4W);  OC=108; K=972;  Kp=1024; IC=108; blk -= 1856; }
  int e = blk * 256 + threadIdx.x;
  int oc = e / Kp, k = e - oc * Kp;
  float v = 0.f;
  if (oc < OC) {
    int NCB = (IC + 15) >> 4;
    if (k < NCB * 144) {
      int cb = k / 144, r = k - cb*144;
      int n = r >> 4, ci = cb*16 + (r & 15);
      if (ci < IC) v = src[(size_t)oc*K + ci*9 + n];
    }
  }
  dst[e] = f2bf(v);
}

// Transpose c5w/c6w to [k][OC] f32 for the tail convs.
// NOTE: must run after conv2 (writes land inside h1's dead region).
__global__ __launch_bounds__(256) void k_packT(
    const float* __restrict__ s5, const float* __restrict__ s6,
    char* __restrict__ ws) {
  int e = blockIdx.x * 256 + threadIdx.x;
  if (e < 124416) {                       // c5: 972 x 128
    int k = e >> 7, oc = e & 127;
    ((float*)(ws + PT5_B))[e] = s5[(size_t)oc*972 + k];
  } else if (e < 124416 + 147456) {       // c6: 1152 x 128
    int e2 = e - 124416;
    int k = e2 >> 7, oc = e2 & 127;
    ((float*)(ws + PT6_B))[e2] = s6[(size_t)oc*1152 + k];
  }
}

// ---------------------------------------------------------------------------
// Deform MFMA GEMM — r21 schedule + MROWS/NSPL knobs. r25 FINAL form:
// f32 X staging [pos][16ci], quad-rotated by (pos>>1)&3 (r26's bf16-X cut
// conflicts 2.1x but lengthened the gather->interp->cvt dependency chain:
// 70.6->75.2µs — dgemm is dependency-bound; f32 staging is optimal).
// dgemm1 = MROWS 128, NSPL 1. dgemm3 = MROWS 64, NSPL 2 (idle-CU split).
// ---------------------------------------------------------------------------
template<int IC, int OC, int OCPAD, int NT, int H, int W, bool ROLLING,
         int MROWS = 64, int NSPL = 1>
__global__ __launch_bounds__(MROWS*4, 2) void k_dgemm(
    const float* __restrict__ in,              // [128,IC,H,W] f32
    const unsigned short* __restrict__ offb,   // [128,18,H,W] bf16
    const unsigned short* __restrict__ wpk,    // packed bf16-hi [NSPL*OCPAD][KPAD] k'
    const float* __restrict__ bng, const float* __restrict__ bnb,
    const float* __restrict__ bnm, const float* __restrict__ bnv,
    float* __restrict__ out) {                 // [128,OC,H,W] f32
  constexpr int NTH  = MROWS * 4;
  constexpr int HW   = H * W;
  constexpr int NCB  = (IC + 15) >> 4;
  constexpr int KV   = NCB * 144;
  constexpr int NP   = (KV + 63) / 64;
  constexpr int KPAD = NP * 64;
  constexpr int TILES = HW / MROWS;
  constexpr int HP = H + 2, WPD = W + 2;
  constexpr int BSZ = OCPAD * 64 * 2;          // [8 kgrp][OCPAD][8] bf16
  constexpr int CHUNKF = HW * 16;              // whole image per 16-ch chunk
  constexpr int SLOTS  = ROLLING ? 2 : NCB;
  constexpr int XSZ    = SLOTS * CHUNKF * 4;
  constexpr int TBL  = MROWS * 9;
  constexpr int TIDX = TBL * 4, TWT = TBL * 16;
  constexpr int PBYTES = TIDX + TWT + BSZ + XSZ;
  constexpr int NBV = (OCPAD * 8 + NTH - 1) / NTH;
  __shared__ __align__(16) char pool[PBYTES];
  uchar4* s_idx = (uchar4*)pool;
  float4* s_wt  = (float4*)(pool + TIDX);
  unsigned short* s_bh = (unsigned short*)(pool + TIDX + TWT);
  float* s_xt = (float*)(pool + TIDX + TWT + BSZ);

  const int tid = threadIdx.x;
  const int grp = blockIdx.x % (TILES * NSPL);
  const int b   = blockIdx.x / (TILES * NSPL);
  const int hw0 = (grp / NSPL) * MROWS;
  const int ns  = grp % NSPL;
  const int oc0 = ns * OCPAD;                  // this block's oc base
  const unsigned short* __restrict__ wpk_s = wpk + (size_t)oc0 * KPAD;
  const float* __restrict__ inb = in + (size_t)b * IC * HW;

  // bilinear table (exact reference formulas; zero-pad folded into weights)
  for (int i = tid; i < TBL; i += NTH) {
    int px2 = i / 9, n = i % 9;
    int h = (hw0 + px2) / W, w = (hw0 + px2) % W;
    float offx = bf2f(offb[(((size_t)b*18 + n)*HW) + h*W + w]);
    float offy = bf2f(offb[(((size_t)b*18 + 9 + n)*HW) + h*W + w]);
    float pxv = (float)(h + n/3) + offx;
    float pyv = (float)(w + n%3) + offy;
    pxv = fminf(fmaxf(pxv, 0.f), (float)(HP - 1));
    pyv = fminf(fmaxf(pyv, 0.f), (float)(WPD - 1));
    float x0 = floorf(pxv), y0 = floorf(pyv);
    float x1 = fminf(x0 + 1.f, (float)(HP - 1));
    float y1 = fminf(y0 + 1.f, (float)(WPD - 1));
    float glt = (1.f + x0 - pxv) * (1.f + y0 - pyv);
    float grb = (1.f - x1 + pxv) * (1.f - y1 + pyv);
    float glb = (1.f + x0 - pxv) * (1.f - y1 + pyv);
    float grt = (1.f - x1 + pxv) * (1.f + y0 - pyv);
    int   cx[4] = {(int)x0, (int)x1, (int)x0, (int)x1};
    int   cy[4] = {(int)y0, (int)y1, (int)y1, (int)y0};
    float gw[4] = {glt, grb, glb, grt};
    unsigned char id[4]; float gg[4];
#pragma unroll
    for (int q = 0; q < 4; ++q) {
      bool ok = (cx[q] >= 1) && (cx[q] <= H) && (cy[q] >= 1) && (cy[q] <= W);
      id[q] = ok ? (unsigned char)((cx[q]-1)*W + (cy[q]-1)) : (unsigned char)0;
      gg[q] = ok ? gw[q] : 0.f;
    }
    s_idx[i] = make_uchar4(id[0], id[1], id[2], id[3]);
    s_wt[i]  = make_float4(gg[0], gg[1], gg[2], gg[3]);
  }

  // stage one 16-channel chunk as [pos][16ci], quad-rotated by (pos>>1)&3.
  auto stageX = [&](int cb) {
    const int slot = ROLLING ? (cb & 1) : cb;
    float* dst = s_xt + (size_t)slot * CHUNKF;
    for (int u = tid; u < HW * 4; u += NTH) {
      const int pp = u & (HW - 1);
      const int qj = u / HW;
      float4 v4;
#pragma unroll
      for (int i2 = 0; i2 < 4; ++i2) {
        int ci = cb*16 + qj*4 + i2;
        ((float*)&v4)[i2] = (ci < IC) ? inb[(size_t)ci*HW + pp] : 0.f;
      }
      *(float4*)(dst + pp*16 + ((((pp >> 1) + qj) & 3) << 2)) = v4;
    }
  };
  if (ROLLING) stageX(0);
  else { for (int cb = 0; cb < NCB; ++cb) stageX(cb); }
  int staged = 0;

  const int lane = tid & 63;
  const int wv   = tid >> 6;
  const int m16  = lane & 15;
  const int quad = lane >> 4;
  const int pv   = wv*16 + m16;          // this thread's MFMA A row (pixel)
  const int tbase = pv * 9;
  f32x4 acc[NT];
#pragma unroll
  for (int nt = 0; nt < NT; ++nt) acc[nt] = (f32x4){0.f, 0.f, 0.f, 0.f};
  short8 rb[NBV];

  auto prefB = [&](int p) {
    if (p >= NP) return;
    const int k0 = p * 64;
#pragma unroll
    for (int j = 0; j < NBV; ++j) {
      int e = tid + NTH*j;
      if (e < OCPAD*8) {
        int oc = e >> 3, kq = e & 7;
        rb[j] = *(const short8*)(wpk_s + (size_t)oc*KPAD + k0 + kq*8);
      }
    }
  };
  auto commitB = [&]() {
#pragma unroll
    for (int j = 0; j < NBV; ++j) {
      int e = tid + NTH*j;
      if (e < OCPAD*8) {
        int oc = e >> 3, kq = e & 7;
        *(short8*)&s_bh[(kq*OCPAD + (oc ^ ((kq*2)&7)))*8] = rb[j];
      }
    }
  };

  // Build one 8-wide A slice (k' = kk..kk+7) for pixel pv, in registers.
  auto buildA = [&](int kk, short8& ahv, short8& alv) {
    float v[8];
    if (kk < KV) {
      const int cb2 = kk / 144;
      const int rem = kk - cb2*144;
      const int n   = rem >> 4;
      const int g0  = (rem >> 2) & 2;          // half*2: logical group base
      const int slot = ROLLING ? (cb2 & 1) : cb2;
      const float* xb = s_xt + (size_t)slot * CHUNKF;
      uchar4 t4 = s_idx[tbase + n];
      float4 w4 = s_wt[tbase + n];
      const int r0i = (int)t4.x, r1i = (int)t4.y;
      const int r2i = (int)t4.z, r3i = (int)t4.w;
      const float* r0 = xb + r0i * 16;
      const float* r1 = xb + r1i * 16;
      const float* r2 = xb + r2i * 16;
      const float* r3 = xb + r3i * 16;
      float4 A0[2], A1[2], A2[2], A3[2];
#pragma unroll
      for (int j = 0; j < 2; ++j) {
        A0[j] = *(const float4*)(r0 + ((((r0i >> 1) + g0 + j) & 3) << 2));
        A1[j] = *(const float4*)(r1 + ((((r1i >> 1) + g0 + j) & 3) << 2));
        A2[j] = *(const float4*)(r2 + ((((r2i >> 1) + g0 + j) & 3) << 2));
        A3[j] = *(const float4*)(r3 + ((((r3i >> 1) + g0 + j) & 3) << 2));
      }
#pragma unroll
      for (int j = 0; j < 2; ++j) {
        v[4*j+0] = w4.x*A0[j].x + w4.y*A1[j].x + w4.z*A2[j].x + w4.w*A3[j].x;
        v[4*j+1] = w4.x*A0[j].y + w4.y*A1[j].y + w4.z*A2[j].y + w4.w*A3[j].y;
        v[4*j+2] = w4.x*A0[j].z + w4.y*A1[j].z + w4.z*A2[j].z + w4.w*A3[j].z;
        v[4*j+3] = w4.x*A0[j].w + w4.y*A1[j].w + w4.z*A2[j].w + w4.w*A3[j].w;
      }
    } else {
#pragma unroll
      for (int i = 0; i < 8; ++i) v[i] = 0.f;
    }
    unsigned hp[4], lp[4];
#pragma unroll
    for (int i = 0; i < 4; ++i) {
      unsigned h = cvtpk(v[2*i], v[2*i+1]);
      float h0 = __uint_as_float(h << 16);
      float h1 = __uint_as_float(h & 0xFFFF0000u);
      hp[i] = h;
      lp[i] = cvtpk(v[2*i] - h0, v[2*i+1] - h1);
    }
    uint4 uh = make_uint4(hp[0], hp[1], hp[2], hp[3]);
    uint4 ul = make_uint4(lp[0], lp[1], lp[2], lp[3]);
    ahv = *(short8*)&uh;
    alv = *(short8*)&ul;
  };

  prefB(0);
  __syncthreads();

  for (int p = 0; p < NP; ++p) {
    short8 ah[2], al[2];
    buildA(p*64 +      quad*8, ah[0], al[0]);
    buildA(p*64 + 32 + quad*8, ah[1], al[1]);
    commitB();
    if (ROLLING) {
      // folded roll staging: no extra barriers (safety proof r21)
      int want = ((p + 1) * 64 + 63) / 144;
      if (want >= NCB) want = NCB - 1;
      if (want > staged) { stageX(want); staged = want; }
    }
    prefB(p + 1);
    __syncthreads();   // writes (commitB/stageX) visible; phase boundary
#pragma unroll
    for (int ks = 0; ks < 2; ++ks) {
      const int kg = ks*4 + quad;
      const int xm = (kg*2) & 7;
#pragma unroll
      for (int nt = 0; nt < NT; ++nt) {
        short8 bh = *(const short8*)&s_bh[(kg*OCPAD + ((nt*16 + m16) ^ xm))*8];
        acc[nt] = MFMA16(ah[ks], bh, acc[nt]);
        acc[nt] = MFMA16(al[ks], bh, acc[nt]);
      }
    }
    __syncthreads();   // read phase done before next iter's writes
  }

  // epilogue: BN + ReLU, f32 out
#pragma unroll
  for (int nt = 0; nt < NT; ++nt) {
    int oc = oc0 + nt*16 + m16;
    if (oc < OC) {
      float sc = bng[oc] * rsqrtf(bnv[oc] + 1e-5f);
      float sh = bnb[oc] - bnm[oc] * sc;
#pragma unroll
      for (int reg = 0; reg < 4; ++reg) {
        int rowl = wv*16 + quad*4 + reg;
        float e = fmaxf(acc[nt][reg] * sc + sh, 0.f);
        out[((size_t)b*OC + oc)*HW + hw0 + rowl] = e;
      }
    }
  }
}

// ---------------------------------------------------------------------------
// Conv MFMA GEMM — r21 form + r25 NSPL (oc-split across blocks; split's
// duplicate staging/buildV lands on otherwise-idle CUs for the 128-block
// layers). s_out/pooling localized to this block's oc range.
// ---------------------------------------------------------------------------
template<int IC, int OC, int OCPAD, int NT, int H, int W,
         bool HASBIAS, bool HASBN, bool RELU, int OUTMODE, int MINW, bool ALO,
         int NSPL = 1>
__global__ __launch_bounds__(256, MINW) void k_gemm(
    const float* __restrict__ in,
    const unsigned short* __restrict__ wpk,    // packed bf16-hi [NSPL*OCPAD][KPAD] k'
    const float* __restrict__ bias,
    const float* __restrict__ bng, const float* __restrict__ bnb,
    const float* __restrict__ bnm, const float* __restrict__ bnv,
    void* __restrict__ outv) {
  constexpr int HW   = H * W;
  constexpr int NCB  = (IC + 15) >> 4;
  constexpr int KV   = NCB * 144;
  constexpr int NP   = (KV + 63) / 64;
  constexpr int KPAD = NP * 64;
  constexpr int TILES = HW / 64;
  constexpr int RT   = 64 / W;               // tile rows
  constexpr int HR   = RT + 2, WPD = W + 2;  // halo dims
  constexpr int HPOS = HR * WPD;
  constexpr int SROW = 20;                   // floats per halo position
  constexpr int CHUNKF = HPOS * SROW;
  constexpr int XSZ  = 2 * CHUNKF * 4;       // 2 rolling slots
  constexpr int BSLOT = OCPAD * 64;          // shorts per B slot
  constexpr int BSZ  = 2 * BSLOT * 2;        // 2 slots
  constexpr int PBST = BSZ + XSZ;
  constexpr int SOUTB = (OUTMODE == 2) ? 64 * (OCPAD + 1) * 4 : 0;
  constexpr int PBYTES = (PBST > SOUTB) ? PBST : SOUTB;
  constexpr int NBV = (OCPAD * 8 + 255) / 256;
  __shared__ __align__(16) char pool[PBYTES];
  unsigned short* s_bh = (unsigned short*)pool;
  float* s_xt  = (float*)(pool + BSZ);
  float* s_out = (float*)pool;

  const int tid = threadIdx.x;
  const int grp = blockIdx.x % (TILES * NSPL);
  const int b   = blockIdx.x / (TILES * NSPL);
  const int hw0 = (grp / NSPL) * 64;
  const int ns  = grp % NSPL;
  const int oc0 = ns * OCPAD;                // this block's oc base
  const unsigned short* __restrict__ wpk_s = wpk + (size_t)oc0 * KPAD;
  const int r0  = hw0 / W;                   // first image row of tile
  const float* __restrict__ inb = in + (size_t)b * IC * HW;

  const int lane = tid & 63;
  const int wv   = tid >> 6;
  const int m16  = lane & 15;
  const int quad = lane >> 4;
  const int pv   = wv*16 + m16;              // MFMA A row (tile-local pixel)
  const int lr   = pv / W, lc = pv % W;
  f32x4 acc[NT];
#pragma unroll
  for (int nt = 0; nt < NT; ++nt) acc[nt] = (f32x4){0.f, 0.f, 0.f, 0.f};
  short8 rb[NBV];

  // stage chunk cb as zero-padded halo [hpos][16ci] (stride SROW).
  auto stageX = [&](int cb) {
    float* dst = s_xt + (size_t)(cb & 1) * CHUNKF;
    for (int e = tid; e < HPOS * 4; e += 256) {
      int pos = e >> 2, g = e & 3;
      int hr = pos / WPD, hc = pos % WPD;
      int ir = r0 + hr - 1, ic = hc - 1;
      bool okp = (ir >= 0) && (ir < H) && (ic >= 0) && (ic < W);
      float4 v4;
#pragma unroll
      for (int i2 = 0; i2 < 4; ++i2) {
        int ci = cb*16 + g*4 + i2;
        ((float*)&v4)[i2] = (okp && ci < IC) ? inb[(size_t)ci*HW + ir*W + ic] : 0.f;
      }
      *(float4*)(dst + (size_t)pos*SROW + g*4) = v4;
    }
  };

  auto prefB = [&](int p) {
    if (p >= NP) return;
    const int k0 = p * 64;
#pragma unroll
    for (int j = 0; j < NBV; ++j) {
      int e = tid + 256*j;
      if (e < OCPAD*8) {
        int oc = e >> 3, kq = e & 7;
        rb[j] = *(const short8*)(wpk_s + (size_t)oc*KPAD + k0 + kq*8);
      }
    }
  };
  auto commitB = [&](int slot) {
    unsigned short* sb = s_bh + (size_t)slot * BSLOT;
#pragma unroll
    for (int j = 0; j < NBV; ++j) {
      int e = tid + 256*j;
      if (e < OCPAD*8) {
        int oc = e >> 3, kq = e & 7;
        *(short8*)&sb[(kq*OCPAD + (oc ^ ((kq*2)&7)))*8] = rb[j];
      }
    }
  };

  // Build one 8-wide A slice (k' = kk..kk+7): 8 consecutive ci at tap n.
  auto buildV = [&](int kk, short8& ahv, short8& alv) {
    float v[8];
    if (kk < KV) {
      const int cb2 = kk / 144;
      const int rem = kk - cb2*144;
      const int n   = rem >> 4;
      const int g0  = (rem >> 2) & 2;        // 0 or 2: which 8-ci half
      const float* xb = s_xt + (size_t)(cb2 & 1) * CHUNKF;
      const int hpos = (lr + n/3) * WPD + (lc + n%3);
      const float* rowp = xb + (size_t)hpos * SROW;
      float4 a0 = *(const float4*)(rowp + g0*4);
      float4 a1 = *(const float4*)(rowp + (g0+1)*4);
      v[0]=a0.x; v[1]=a0.y; v[2]=a0.z; v[3]=a0.w;
      v[4]=a1.x; v[5]=a1.y; v[6]=a1.z; v[7]=a1.w;
    } else {
#pragma unroll
      for (int i = 0; i < 8; ++i) v[i] = 0.f;
    }
    unsigned hp[4], lp[4];
#pragma unroll
    for (int i = 0; i < 4; ++i) {
      unsigned h = cvtpk(v[2*i], v[2*i+1]);
      hp[i] = h;
      if constexpr (ALO) {
        float h0 = __uint_as_float(h << 16);
        float h1 = __uint_as_float(h & 0xFFFF0000u);
        lp[i] = cvtpk(v[2*i] - h0, v[2*i+1] - h1);
      }
    }
    uint4 uh = make_uint4(hp[0], hp[1], hp[2], hp[3]);
    ahv = *(short8*)&uh;
    if constexpr (ALO) {
      uint4 ul = make_uint4(lp[0], lp[1], lp[2], lp[3]);
      alv = *(short8*)&ul;
    }
  };

  stageX(0);
  prefB(0);
  int staged = 0;
  __syncthreads();

  for (int p = 0; p < NP; ++p) {
    short8 ah[2], al[2];
    buildV(p*64 +      quad*8, ah[0], al[0]);
    buildV(p*64 + 32 + quad*8, ah[1], al[1]);
    commitB(p & 1);
    prefB(p + 1);
    {   // roll staging (block-uniform condition; opposite x-slot)
      int want = ((p + 1) * 64 + 63) / 144;
      if (want >= NCB) want = NCB - 1;
      if (want > staged) { stageX(want); staged = want; }
    }
    __syncthreads();   // B[p] + staged chunk visible; prev-iter reads done
    const unsigned short* sb = s_bh + (size_t)(p & 1) * BSLOT;
#pragma unroll
    for (int ks = 0; ks < 2; ++ks) {
      const int kg = ks*4 + quad;
      const int xm = (kg*2) & 7;
#pragma unroll
      for (int nt = 0; nt < NT; ++nt) {
        short8 bh = *(const short8*)&sb[(kg*OCPAD + ((nt*16 + m16) ^ xm))*8];
        acc[nt] = MFMA16(ah[ks], bh, acc[nt]);
        if constexpr (ALO) acc[nt] = MFMA16(al[ks], bh, acc[nt]);
      }
    }
  }

  constexpr int OCS = OCPAD + 1;
  if constexpr (OUTMODE == 2) {
    __syncthreads();   // lagging MFMA reads of s_bh done before s_out clobbers
  }
#pragma unroll
  for (int nt = 0; nt < NT; ++nt) {
    int ocl = nt*16 + m16;
    int oc  = oc0 + ocl;
    float bi = 0.f, sc = 1.f, sh = 0.f;
    if (oc < OC) {
      if constexpr (HASBIAS) bi = bias[oc];
      if constexpr (HASBN) {
        sc = bng[oc] * rsqrtf(bnv[oc] + 1e-5f);
        sh = bnb[oc] - bnm[oc] * sc;
      }
    }
#pragma unroll
    for (int reg = 0; reg < 4; ++reg) {
      int rowl = wv*16 + quad*4 + reg;
      float e = (acc[nt][reg] + bi) * sc + sh;
      if constexpr (RELU) e = fmaxf(e, 0.f);
      if (oc < OC) {
        if constexpr (OUTMODE == 1) {
          ((unsigned short*)outv)[((size_t)b*OC + oc)*HW + hw0 + rowl] = f2bf(e);
        } else {
          s_out[rowl*OCS + ocl] = e;
        }
      }
    }
  }
  if constexpr (OUTMODE == 2) {
    __syncthreads();
    constexpr int PR = (64 / W) / 2, PC = W / 2;
    const int OCL = (OC - oc0 < OCPAD) ? (OC - oc0) : OCPAD;
    const int CNT = PR * PC * OCL;
    float* out = (float*)outv;
    for (int e2 = tid; e2 < CNT; e2 += 256) {
      int ocl = e2 % OCL, q = e2 / OCL, pc2 = q % PC, pr2 = q / PC;
      int base = ((2*pr2)*W + 2*pc2)*OCS + ocl;
      float a0 = s_out[base],         a1 = s_out[base + OCS];
      float a2 = s_out[base + W*OCS], a3 = s_out[base + W*OCS + OCS];
      float m = fmaxf(fmaxf(a0, a1), fmaxf(a2, a3));
      out[(((size_t)b*OC + oc0 + ocl)*(H/2) + (r0 >> 1) + pr2)*(W/2) + pc2] = m;
    }
  }
}

// ---------------------------------------------------------------------------
// Tail conv (4x4 spatial): block = (batch, 32-oc group), ONE barrier.
// Input staged zero-padded 6x6 per channel; weights pre-transposed [k][OC].
// Thread = (oc, 2-pixel row pair). POOLAVG fuses ReLU-then-avgpool via
// __shfl_xor(.,2) (partner pixel-pair is 2 lanes away) -> writes [b][512].
// ---------------------------------------------------------------------------
template<int IC, int OC, bool POOLAVG>
__global__ __launch_bounds__(256, 4) void k_tail(
    const float* __restrict__ in,     // [128, IC, 4, 4]
    const float* __restrict__ wt,     // [IC*9][OC] f32 (transposed)
    const float* __restrict__ bias,
    const float* __restrict__ bng, const float* __restrict__ bnb,
    const float* __restrict__ bnm, const float* __restrict__ bnv,
    float* __restrict__ out) {
  constexpr int NB = OC / 32;
  __shared__ float s_pad[IC * 36];
  const int tid = threadIdx.x;
  const int b = blockIdx.x / NB;
  const int g = blockIdx.x % NB;
  for (int i = tid; i < IC*36; i += 256) {
    int ci = i / 36, pos = i % 36;
    int rr = pos / 6 - 1, cc = pos % 6 - 1;
    bool ok = (rr >= 0) && (rr < 4) && (cc >= 0) && (cc < 4);
    s_pad[i] = ok ? in[((size_t)b*IC + ci)*16 + rr*4 + cc] : 0.f;
  }
  __syncthreads();
  const int oc = g*32 + (tid >> 3);
  const int p  = tid & 7;                 // pixel-pair index
  const int r0 = p >> 1, c0 = (p & 1) * 2;
  float a0 = 0.f, a1 = 0.f;
  const float* wp = wt + oc;
#pragma unroll 2
  for (int ci = 0; ci < IC; ++ci) {
    const float* sp = s_pad + ci*36 + r0*6 + c0;
#pragma unroll
    for (int n = 0; n < 9; ++n) {
      float wv = wp[(size_t)(ci*9 + n)*OC];
      float v0 = sp[(n/3)*6 + (n%3)];
      float v1 = sp[(n/3)*6 + (n%3) + 1];
      a0 = fmaf(wv, v0, a0);
      a1 = fmaf(wv, v1, a1);
    }
  }
  float sc = bng[oc] * rsqrtf(bnv[oc] + 1e-5f);
  float sh = bnb[oc] - bnm[oc]*sc;
  float bi = bias[oc];
  float e0 = fmaxf((a0 + bi)*sc + sh, 0.f);
  float e1 = fmaxf((a1 + bi)*sc + sh, 0.f);
  if constexpr (!POOLAVG) {
    size_t ob = ((size_t)b*OC + oc)*16 + r0*4 + c0;
    out[ob]     = e0;
    out[ob + 1] = e1;
  } else {
    float s = e0 + e1;
    float tot = s + __shfl_xor(s, 2);
    if ((p & 2) == 0) {
      int pr = p >> 2, pc = p & 1;
      out[(size_t)b*512 + oc*4 + pr*2 + pc] = tot * 0.25f;
    }
  }
}

__global__ __launch_bounds__(128) void k_fc(const float* __restrict__ in,
                                            const float* __restrict__ w,
                                            const float* __restrict__ bias,
                                            float* __restrict__ out) {
  int j = blockIdx.x, b = threadIdx.x;
  const float4* ib = (const float4*)(in + (size_t)b*512);
  const float4* wb = (const float4*)(w + (size_t)j*512);
  float acc = bias[j];
  for (int k = 0; k < 128; ++k) {
    float4 a = ib[k], q = wb[k];
    acc = fmaf(a.x, q.x, fmaf(a.y, q.y, fmaf(a.z, q.z, fmaf(a.w, q.w, acc))));
  }
  out[(size_t)b*200 + j] = acc;
}

__global__ __launch_bounds__(128) void k_fc1(const float* __restrict__ in,
                                             const float* __restrict__ w,
                                             const float* __restrict__ bias,
                                             float* __restrict__ out) {
  int j = blockIdx.x, b = threadIdx.x;
  const float4* ib = (const float4*)(in + (size_t)b*200);
  const float4* wb = (const float4*)(w + (size_t)j*200);
  float acc = bias[j];
  for (int k = 0; k < 50; ++k) {
    float4 a = ib[k], q = wb[k];
    acc = fmaf(a.x, q.x, fmaf(a.y, q.y, fmaf(a.z, q.z, fmaf(a.w, q.w, acc))));
  }
  out[(size_t)b*16 + j] = acc;
}

// ---------------------------------------------------------------------------
extern "C" void kernel_launch(void* const* d_in, const int* in_sizes, int n_in,
                              void* d_out, int out_size, void* d_ws, size_t ws_size,
                              hipStream_t stream) {
  const float* X    = (const float*)d_in[0];
  const float* D1PW = (const float*)d_in[1];
  const float* D1PB = (const float*)d_in[2];
  const float* D1W  = (const float*)d_in[3];
  const float* BN1G = (const float*)d_in[4];
  const float* BN1B = (const float*)d_in[5];
  const float* BN1M = (const float*)d_in[6];
  const float* BN1V = (const float*)d_in[7];
  const float* C2W  = (const float*)d_in[8];
  const float* C2B  = (const float*)d_in[9];
  const float* BN2G = (const float*)d_in[10];
  const float* BN2B = (const float*)d_in[11];
  const float* BN2M = (const float*)d_in[12];
  const float* BN2V = (const float*)d_in[13];
  const float* D3PW = (const float*)d_in[14];
  const float* D3PB = (const float*)d_in[15];
  const float* D3W  = (const float*)d_in[16];
  const float* BN3G = (const float*)d_in[17];
  const float* BN3B = (const float*)d_in[18];
  const float* BN3M = (const float*)d_in[19];
  const float* BN3V = (const float*)d_in[20];
  const float* C4W  = (const float*)d_in[21];
  const float* C4B  = (const float*)d_in[22];
  const float* BN4G = (const float*)d_in[23];
  const float* BN4B = (const float*)d_in[24];
  const float* BN4M = (const float*)d_in[25];
  const float* BN4V = (const float*)d_in[26];
  const float* C5W  = (const float*)d_in[27];
  const float* C5B  = (const float*)d_in[28];
  const float* BN5G = (const float*)d_in[29];
  const float* BN5B = (const float*)d_in[30];
  const float* BN5M = (const float*)d_in[31];
  const float* BN5V = (const float*)d_in[32];
  const float* C6W  = (const float*)d_in[33];
  const float* C6B  = (const float*)d_in[34];
  const float* BN6G = (const float*)d_in[35];
  const float* BN6B = (const float*)d_in[36];
  const float* BN6M = (const float*)d_in[37];
  const float* BN6V = (const float*)d_in[38];
  const float* FCW  = (const float*)d_in[39];
  const float* FCB  = (const float*)d_in[40];
  const float* FC1W = (const float*)d_in[41];
  const float* FC1B = (const float*)d_in[42];

  char* ws = (char*)d_ws;
  unsigned short* pk_d1pw = (unsigned short*)(ws + PK_D1PW);
  unsigned short* pk_d1w  = (unsigned short*)(ws + PK_D1W);
  unsigned short* pk_c2w  = (unsigned short*)(ws + PK_C2W);
  unsigned short* pk_d3pw = (unsigned short*)(ws + PK_D3PW);
  unsigned short* pk_d3w  = (unsigned short*)(ws + PK_D3W);
  unsigned short* pk_c4w  = (unsigned short*)(ws + PK_C4W);
  unsigned short* off1 = (unsigned short*)(ws + OFF1_B);
  unsigned short* off3 = (unsigned short*)(ws + OFF3_B);
  float* h1   = (float*)(ws + H1_B);
  float* h2p  = (float*)(ws + H2P_B);
  float* h3   = (float*)(ws + H3_B);
  float* h4p  = (float*)(ws + H4P_B);
  float* h5   = (float*)(ws + H5_B);
  float* h6p  = (float*)(ws + H6P_B);
  float* fco  = (float*)(ws + FCO_B);
  float* pt5  = (float*)(ws + PT5_B);
  float* pt6  = (float*)(ws + PT6_B);
  float* outp = (float*)d_out;

  // weight pre-pack (bf16 hi planes; ALL tensors k' order; d3w/c4w 128 rows)
  k_pack6<<<2368, 256, 0, stream>>>(D1PW, D1W, C2W, D3PW, D3W, C4W, ws);

  // block 1: offset conv (A-hi only) -> deform einsum + BN + ReLU
  k_gemm<200,18,32,2,16,16,true,false,false,1,3,false><<<512, 256, 0, stream>>>(
      X, pk_d1pw, D1PB, nullptr, nullptr, nullptr, nullptr, off1);
  // dgemm1: MROWS=128, f32-X staging (r25 best: 70.6µs)
  k_dgemm<200,96,96,6,16,16,true,128><<<256, 512, 0, stream>>>(
      X, off1, pk_d1w, BN1G, BN1B, BN1M, BN1V, h1);
  // block 2: conv + bias + BN + ReLU + maxpool
  k_gemm<96,96,96,6,16,16,true,true,true,2,3,true><<<512, 256, 0, stream>>>(
      h1, pk_c2w, C2B, BN2G, BN2B, BN2M, BN2V, h2p);
  // tail-conv weight transpose — h1 now dead; pt5/pt6 live inside its span
  k_packT<<<1062, 256, 0, stream>>>(C5W, C6W, ws);
  // block 3: offset conv, NSPL=2 (grid 128->256; was half-machine idle)
  k_gemm<96,18,16,1,8,8,true,false,false,1,3,false,2><<<256, 256, 0, stream>>>(
      h2p, pk_d3pw, D3PB, nullptr, nullptr, nullptr, nullptr, off3);
  // dgemm3: NSPL=2 (grid 128->256)
  k_dgemm<96,108,64,4,8,8,false,64,2><<<256, 256, 0, stream>>>(
      h2p, off3, pk_d3w, BN3G, BN3B, BN3M, BN3V, h3);
  // block 4: conv + maxpool, NSPL=2 (grid 128->256)
  k_gemm<108,108,64,4,8,8,true,true,true,2,3,true,2><<<256, 256, 0, stream>>>(
      h3, pk_c4w, C4B, BN4G, BN4B, BN4M, BN4V, h4p);
  // block 5: conv + BN + ReLU (tail, 512 blocks)
  k_tail<108,128,false><<<512, 256, 0, stream>>>(
      h4p, pt5, C5B, BN5G, BN5B, BN5M, BN5V, h5);
  // block 6: conv + BN + ReLU + avgpool (tail, fused)
  k_tail<128,128,true><<<512, 256, 0, stream>>>(
      h5, pt6, C6B, BN6G, BN6B, BN6M, BN6V, h6p);
  // classifier
  k_fc<<<200, 128, 0, stream>>>(h6p, FCW, FCB, fco);
  k_fc1<<<16, 128, 0, stream>>>(fco, FC1W, FC1B, outp);
}